// Round 4
// baseline (1262.907 us; speedup 1.0000x reference)
//
#include <hip/hip_runtime.h>
#include <math.h>

#define TDIM 1024
#define DDIM 256
#define BDIM 64

typedef float f32x2 __attribute__((ext_vector_type(2)));

__device__ __forceinline__ float tanh_fast(float z) {
    return 1.f - 2.f / (1.f + __expf(2.f * z));
}

// ---------------------------------------------------------------------------
// Kernel A: P[m][n] = sum_k x[m][k]*U[k][n] + b[n].  M=65536, N=K=256.
// BM=64, BN=256, BK=32, 256 thr, 8x8 micro-tile, register-prefetch dbuf.
// ---------------------------------------------------------------------------
__global__ __launch_bounds__(256, 3)
void xu_gemm(const float* __restrict__ x, const float* __restrict__ U,
             const float* __restrict__ bias, float* __restrict__ P)
{
    __shared__ __align__(16) float As[32][64];   // [k][m] transposed A tile
    __shared__ __align__(16) float Bs[32][256];  // [k][n]
    const int tid = threadIdx.x;
    const int tr = tid >> 5;   // 0..7
    const int tc = tid & 31;   // 0..31
    const long rowBase = (long)blockIdx.x * 64;

    float acc[8][8];
#pragma unroll
    for (int r = 0; r < 8; ++r)
#pragma unroll
        for (int c = 0; c < 8; ++c) acc[r][c] = 0.f;

    float4 xs[2], us[8];
#define LOADX(K0) _Pragma("unroll") \
    for (int s_ = 0; s_ < 2; ++s_) { int idx = tid*2+s_; int r_ = idx>>3; int kq = idx&7; \
        xs[s_] = *(const float4*)&x[(rowBase + r_)*256 + (K0) + kq*4]; }
#define LOADU(K0) _Pragma("unroll") \
    for (int s_ = 0; s_ < 8; ++s_) { int idx = tid + s_*256; int kk_ = idx>>6; int c4 = idx&63; \
        us[s_] = *(const float4*)&U[((K0)+kk_)*256 + c4*4]; }

    LOADX(0); LOADU(0);

    for (int k0 = 0; k0 < 256; k0 += 32) {
        // staged regs -> LDS
#pragma unroll
        for (int s_ = 0; s_ < 2; ++s_) {
            int idx = tid*2+s_; int r_ = idx>>3; int kq = idx&7;
            As[kq*4+0][r_] = xs[s_].x; As[kq*4+1][r_] = xs[s_].y;
            As[kq*4+2][r_] = xs[s_].z; As[kq*4+3][r_] = xs[s_].w;
        }
#pragma unroll
        for (int s_ = 0; s_ < 8; ++s_) {
            int idx = tid + s_*256; int kk_ = idx>>6; int c4 = idx&63;
            *(float4*)&Bs[kk_][c4*4] = us[s_];
        }
        __syncthreads();
        if (k0 < 224) { LOADX(k0 + 32); LOADU(k0 + 32); }  // in flight over compute
#pragma unroll
        for (int kk = 0; kk < 32; ++kk) {
            float4 a0 = *(const float4*)&As[kk][tr*4];
            float4 a1 = *(const float4*)&As[kk][tr*4 + 32];
            float4 b0 = *(const float4*)&Bs[kk][tc*4];
            float4 b1 = *(const float4*)&Bs[kk][tc*4 + 128];
            float av[8] = {a0.x,a0.y,a0.z,a0.w,a1.x,a1.y,a1.z,a1.w};
            float bv[8] = {b0.x,b0.y,b0.z,b0.w,b1.x,b1.y,b1.z,b1.w};
#pragma unroll
            for (int r = 0; r < 8; ++r)
#pragma unroll
                for (int c = 0; c < 8; ++c)
                    acc[r][c] = fmaf(av[r], bv[c], acc[r][c]);
        }
        __syncthreads();
    }

    float4 bb0 = *(const float4*)&bias[tc*4];
    float4 bb1 = *(const float4*)&bias[tc*4 + 128];
#pragma unroll
    for (int r = 0; r < 8; ++r) {
        long row = rowBase + (r < 4 ? (tr*4 + r) : (32 + tr*4 + (r - 4)));
        float4 lo = make_float4(acc[r][0] + bb0.x, acc[r][1] + bb0.y,
                                acc[r][2] + bb0.z, acc[r][3] + bb0.w);
        float4 hi = make_float4(acc[r][4] + bb1.x, acc[r][5] + bb1.y,
                                acc[r][6] + bb1.z, acc[r][7] + bb1.w);
        *(float4*)&P[row * 256 + tc*4]       = lo;
        *(float4*)&P[row * 256 + tc*4 + 128] = hi;
    }
}

// ---------------------------------------------------------------------------
// Kernel B: sequential scan, 1 block/row, 1024 thr = 16 waves.
//   tid -> (jp = tid>>3: column pair, q = tid&7: 32-wide k-octant).
//   q lives in lane bits 0..2  ->  shfl_xor(1,2,4) butterfly reduces the
//   8 K-split partials in-wave; ONE barrier per step.
//   W fragment in regs (64 VGPR) stored in ROTATED chunk order c=(i+q)&7 so
//   the LDS state reads hit banks ((i+q)&7)*4 -> conflict-free, and all
//   register indices stay compile-time.
//   Depth-2 P prefetch; scan_out[t-1] written at top of step t (off the
//   critical path; P[t+2..] reads always stay ahead of the in-place
//   overwrites).
// ---------------------------------------------------------------------------
__global__ __launch_bounds__(1024, 4)
void rnn_scan(const float* __restrict__ s0, const float* __restrict__ W,
              float* __restrict__ out)
{
    __shared__ __align__(16) float sb0[256];
    __shared__ __align__(16) float sb1[256];

    const int tid = threadIdx.x;
    const int jp  = tid >> 3;   // 0..127 -> columns 2jp, 2jp+1
    const int q   = tid & 7;    // 0..7   -> k in [q*32, q*32+32)
    const int row = blockIdx.x;

    // w2[4*i+u] = W[q*32 + c*4 + u][2jp..2jp+1],  c = (i+q)&7  (rotated)
    f32x2 w2[32];
#pragma unroll
    for (int i = 0; i < 8; ++i) {
        int c = (i + q) & 7;
#pragma unroll
        for (int u = 0; u < 4; ++u)
            w2[4*i+u] = *(const f32x2*)&W[(q*32 + c*4 + u) * 256 + 2*jp];
    }

    float* scanP = out + BDIM * DDIM + (long)row * TDIM * DDIM;

    f32x2 pa = *(const f32x2*)&scanP[2*jp];          // P[0]
    f32x2 pb = *(const f32x2*)&scanP[256 + 2*jp];    // P[1]

    if (tid < 64)
        ((float4*)sb0)[tid] = ((const float4*)(s0 + row * 256))[tid];
    __syncthreads();

#define BODY(T, SIN, SOUT, PREG)                                              \
  {                                                                           \
    if ((T) > 0 && (tid & 63) < 4) {         /* scan_out[T-1], 4 lanes/wave */\
        int fi = ((tid >> 6) << 2) + (tid & 63);                              \
        float4 h4 = ((const float4*)(SIN))[fi];                               \
        *(float4*)&scanP[(long)((T) - 1) * 256 + fi * 4] = h4;                \
    }                                                                         \
    const float4* s4p = (const float4*)(SIN);                                 \
    f32x2 a0 = {0.f, 0.f}, a1 = {0.f, 0.f};                                   \
    _Pragma("unroll")                                                         \
    for (int i = 0; i < 8; ++i) {                                             \
        float4 sv = s4p[q * 8 + ((i + q) & 7)];   /* conflict-free banks */   \
        a0 += w2[4*i]     * sv.x;                                             \
        a1 += w2[4*i + 1] * sv.y;                                             \
        a0 += w2[4*i + 2] * sv.z;                                             \
        a1 += w2[4*i + 3] * sv.w;                                             \
    }                                                                         \
    f32x2 accv = a0 + a1;                                                     \
    float zx = accv.x, zy = accv.y;                                           \
    zx += __shfl_xor(zx, 1); zy += __shfl_xor(zy, 1);                         \
    zx += __shfl_xor(zx, 2); zy += __shfl_xor(zy, 2);                         \
    zx += __shfl_xor(zx, 4); zy += __shfl_xor(zy, 4);                         \
    zx += (PREG).x; zy += (PREG).y;                                           \
    float hx = tanh_fast(zx), hy = tanh_fast(zy);                             \
    if (q == 0) { f32x2 h2; h2.x = hx; h2.y = hy;                             \
                  *(f32x2*)&(SOUT)[2*jp] = h2; }                              \
    __syncthreads();                                                          \
  }

    for (int t = 0; t < TDIM; t += 2) {
        // depth-2 prefetch: consumed two iterations from now
        f32x2 pnA = *(const f32x2*)&scanP[(long)((t + 2) & 1023) * 256 + 2*jp];
        f32x2 pnB = *(const f32x2*)&scanP[(long)((t + 3) & 1023) * 256 + 2*jp];
        BODY(t,     sb0, sb1, pa);
        BODY(t + 1, sb1, sb0, pb);
        pa = pnA; pb = pnB;
    }

    // scan_out[1023] + final state (state lives in sb0 after 1024 steps)
    if (tid < 64) {
        float4 h4 = ((const float4*)sb0)[tid];
        *(float4*)&scanP[(long)(TDIM - 1) * 256 + tid * 4] = h4;
        *(float4*)&out[row * 256 + tid * 4] = h4;
    }
}

extern "C" void kernel_launch(void* const* d_in, const int* in_sizes, int n_in,
                              void* d_out, int out_size, void* d_ws, size_t ws_size,
                              hipStream_t stream) {
    (void)in_sizes; (void)n_in; (void)out_size; (void)d_ws; (void)ws_size;
    const float* s0 = (const float*)d_in[0];
    const float* x  = (const float*)d_in[1];
    const float* W  = (const float*)d_in[2];
    const float* U  = (const float*)d_in[3];
    const float* b  = (const float*)d_in[4];
    float* out = (float*)d_out;
    float* P   = out + BDIM * DDIM;   // scan_out region doubles as P buffer

    xu_gemm<<<dim3(65536 / 64), dim3(256), 0, stream>>>(x, U, b, P);
    rnn_scan<<<dim3(BDIM), dim3(1024), 0, stream>>>(s0, W, out);
}

// Round 5
// 1099.573 us; speedup vs baseline: 1.1485x; 1.1485x over previous
//
#include <hip/hip_runtime.h>
#include <math.h>

#define TDIM 1024
#define DDIM 256
#define BDIM 64

typedef float f32x2 __attribute__((ext_vector_type(2)));

__device__ __forceinline__ float tanh_fast(float z) {
    return 1.f - 2.f / (1.f + __expf(2.f * z));
}

// ---------------------------------------------------------------------------
// Kernel A: P[m][n] = sum_k x[m][k]*U[k][n] + b[n].  M=65536, N=K=256.
// EXACT round-0 version (measured 168 us). BM=64, BN=256, BK=32, 256 thr,
// 8x8 micro-tile.
// ---------------------------------------------------------------------------
__global__ __launch_bounds__(256)
void xu_gemm(const float* __restrict__ x, const float* __restrict__ U,
             const float* __restrict__ bias, float* __restrict__ P)
{
    __shared__ float As[32][64];   // [k][m] transposed A tile
    __shared__ float Bs[32][256];  // [k][n]
    const int tid = threadIdx.x;
    const int tr = tid >> 5;   // 0..7
    const int tc = tid & 31;   // 0..31
    const long rowBase = (long)blockIdx.x * 64;

    float acc[8][8];
#pragma unroll
    for (int r = 0; r < 8; ++r)
#pragma unroll
        for (int c = 0; c < 8; ++c) acc[r][c] = 0.f;

    for (int k0 = 0; k0 < 256; k0 += 32) {
#pragma unroll
        for (int s = 0; s < 2; ++s) {
            int idx = tid * 2 + s;
            int r   = idx >> 3;          // 0..63
            int kq  = idx & 7;           // k-offset kq*4
            float4 v = *(const float4*)&x[(rowBase + r) * 256 + k0 + kq * 4];
            As[kq*4+0][r] = v.x;
            As[kq*4+1][r] = v.y;
            As[kq*4+2][r] = v.z;
            As[kq*4+3][r] = v.w;
        }
#pragma unroll
        for (int s = 0; s < 8; ++s) {
            int idx = tid + s * 256;
            int kk  = idx >> 6;
            int c4  = idx & 63;
            *(float4*)&Bs[kk][c4*4] = *(const float4*)&U[(k0 + kk) * 256 + c4*4];
        }
        __syncthreads();
#pragma unroll
        for (int kk = 0; kk < 32; ++kk) {
            float4 a0 = *(const float4*)&As[kk][tr*4];
            float4 a1 = *(const float4*)&As[kk][tr*4 + 32];
            float4 b0 = *(const float4*)&Bs[kk][tc*4];
            float4 b1 = *(const float4*)&Bs[kk][tc*4 + 128];
            float av[8] = {a0.x,a0.y,a0.z,a0.w,a1.x,a1.y,a1.z,a1.w};
            float bv[8] = {b0.x,b0.y,b0.z,b0.w,b1.x,b1.y,b1.z,b1.w};
#pragma unroll
            for (int r = 0; r < 8; ++r)
#pragma unroll
                for (int c = 0; c < 8; ++c)
                    acc[r][c] = fmaf(av[r], bv[c], acc[r][c]);
        }
        __syncthreads();
    }
    float4 bb0 = *(const float4*)&bias[tc*4];
    float4 bb1 = *(const float4*)&bias[tc*4 + 128];
#pragma unroll
    for (int r = 0; r < 8; ++r) {
        long row = rowBase + (r < 4 ? (tr*4 + r) : (32 + tr*4 + (r - 4)));
        float4 lo = make_float4(acc[r][0] + bb0.x, acc[r][1] + bb0.y,
                                acc[r][2] + bb0.z, acc[r][3] + bb0.w);
        float4 hi = make_float4(acc[r][4] + bb1.x, acc[r][5] + bb1.y,
                                acc[r][6] + bb1.z, acc[r][7] + bb1.w);
        *(float4*)&P[row * 256 + tc*4]       = lo;
        *(float4*)&P[row * 256 + tc*4 + 128] = hi;
    }
}

// ---------------------------------------------------------------------------
// Kernel B: sequential scan, 1 block/row, 1024 thr = 16 waves.
//   Mapping: q = (tid>>3)&7 (k-octant, lane bits 3..5),
//            jp = (tid>>6)*8 + (tid&7) (column pair -> cols 2jp, 2jp+1).
//   -> shfl_xor masks 8,16,32 reduce the 8 K-split partials in-wave.
//   -> a wave's 64 lanes read only 8 DISTINCT float4s from LDS per slot
//      (8 jp-duplicates share each address: HW broadcast), rotated chunk
//      order c=(i+q)&7 puts the 8 addresses in 8 distinct bank groups:
//      conflict-free AND 8x less LDS bank traffic.
//   W fragment (64 VGPR) pinned in registers: amdgpu_waves_per_eu(4,4)
//   gives the 128-VGPR budget (exactly 1 block/CU) and the empty asm
//   redefines each value so the compiler CANNOT rematerialize the loads
//   inside the loop (round-4 failure mode: VGPR=60, W re-read from L2
//   every step, 961 us).
//   Depth-2 P prefetch; scan_out[t-1] written at top of step t.
// ---------------------------------------------------------------------------
__global__ __launch_bounds__(1024)
__attribute__((amdgpu_waves_per_eu(4, 4)))
void rnn_scan(const float* __restrict__ s0, const float* __restrict__ W,
              float* __restrict__ out)
{
    __shared__ __align__(16) float sb0[256];
    __shared__ __align__(16) float sb1[256];

    const int tid = threadIdx.x;
    const int q   = (tid >> 3) & 7;              // k in [q*32, q*32+32)
    const int jp  = ((tid >> 6) << 3) | (tid & 7); // 0..127 -> cols 2jp,2jp+1
    const int row = blockIdx.x;

    // w2[4*i+u] = W[q*32 + c*4 + u][2jp..2jp+1],  c = (i+q)&7  (rotated)
    f32x2 w2[32];
#pragma unroll
    for (int i = 0; i < 8; ++i) {
        int c = (i + q) & 7;
#pragma unroll
        for (int u = 0; u < 4; ++u)
            w2[4*i+u] = *(const f32x2*)&W[(q*32 + c*4 + u) * 256 + 2*jp];
    }
    // Pin: redefine each value in a VGPR -> rematerialization is illegal.
#pragma unroll
    for (int i = 0; i < 32; ++i)
        asm volatile("" : "+v"(w2[i]));

    float* scanP = out + BDIM * DDIM + (long)row * TDIM * DDIM;

    f32x2 pa = *(const f32x2*)&scanP[2*jp];          // P[0]
    f32x2 pb = *(const f32x2*)&scanP[256 + 2*jp];    // P[1]

    if (tid < 64)
        ((float4*)sb0)[tid] = ((const float4*)(s0 + row * 256))[tid];
    __syncthreads();

#define BODY(T, SIN, SOUT, PREG)                                              \
  {                                                                           \
    if ((T) > 0 && (tid & 63) < 4) {         /* scan_out[T-1], 4 lanes/wave */\
        int fi = ((tid >> 6) << 2) + (tid & 63);                              \
        float4 h4 = ((const float4*)(SIN))[fi];                               \
        *(float4*)&scanP[(long)((T) - 1) * 256 + fi * 4] = h4;                \
    }                                                                         \
    const float4* s4p = (const float4*)(SIN);                                 \
    f32x2 a0 = {0.f, 0.f}, a1 = {0.f, 0.f};                                   \
    _Pragma("unroll")                                                         \
    for (int i = 0; i < 8; ++i) {                                             \
        float4 sv = s4p[q * 8 + ((i + q) & 7)];  /* broadcast + no conflict */\
        a0 += w2[4*i]     * sv.x;                                             \
        a1 += w2[4*i + 1] * sv.y;                                             \
        a0 += w2[4*i + 2] * sv.z;                                             \
        a1 += w2[4*i + 3] * sv.w;                                             \
    }                                                                         \
    f32x2 accv = a0 + a1;                                                     \
    float zx = accv.x, zy = accv.y;                                           \
    zx += __shfl_xor(zx, 8);  zy += __shfl_xor(zy, 8);                        \
    zx += __shfl_xor(zx, 16); zy += __shfl_xor(zy, 16);                       \
    zx += __shfl_xor(zx, 32); zy += __shfl_xor(zy, 32);                       \
    zx += (PREG).x; zy += (PREG).y;                                           \
    float hx = tanh_fast(zx), hy = tanh_fast(zy);                             \
    if (q == 0) { f32x2 h2; h2.x = hx; h2.y = hy;                             \
                  *(f32x2*)&(SOUT)[2*jp] = h2; }                              \
    __syncthreads();                                                          \
  }

    for (int t = 0; t < TDIM; t += 2) {
        // depth-2 prefetch: consumed two iterations from now
        f32x2 pnA = *(const f32x2*)&scanP[(long)((t + 2) & 1023) * 256 + 2*jp];
        f32x2 pnB = *(const f32x2*)&scanP[(long)((t + 3) & 1023) * 256 + 2*jp];
        BODY(t,     sb0, sb1, pa);
        BODY(t + 1, sb1, sb0, pb);
        pa = pnA; pb = pnB;
    }

    // scan_out[1023] + final state (state lives in sb0 after 1024 steps)
    if (tid < 64) {
        float4 h4 = ((const float4*)sb0)[tid];
        *(float4*)&scanP[(long)(TDIM - 1) * 256 + tid * 4] = h4;
        *(float4*)&out[row * 256 + tid * 4] = h4;
    }
}

extern "C" void kernel_launch(void* const* d_in, const int* in_sizes, int n_in,
                              void* d_out, int out_size, void* d_ws, size_t ws_size,
                              hipStream_t stream) {
    (void)in_sizes; (void)n_in; (void)out_size; (void)d_ws; (void)ws_size;
    const float* s0 = (const float*)d_in[0];
    const float* x  = (const float*)d_in[1];
    const float* W  = (const float*)d_in[2];
    const float* U  = (const float*)d_in[3];
    const float* b  = (const float*)d_in[4];
    float* out = (float*)d_out;
    float* P   = out + BDIM * DDIM;   // scan_out region doubles as P buffer

    xu_gemm<<<dim3(65536 / 64), dim3(256), 0, stream>>>(x, U, b, P);
    rnn_scan<<<dim3(BDIM), dim3(1024), 0, stream>>>(s0, W, out);
}

// Round 10
// 1068.978 us; speedup vs baseline: 1.1814x; 1.0286x over previous
//
#include <hip/hip_runtime.h>
#include <math.h>

#define TDIM 1024
#define DDIM 256
#define BDIM 64

__device__ __forceinline__ float tanh_fast(float z) {
    return 1.f - 2.f / (1.f + __expf(2.f * z));
}

// ---------------------------------------------------------------------------
// Kernel A: P[m][n] = sum_k x[m][k]*U[k][n] + b[n].  M=65536, N=K=256.
// EXACT round-0 version (measured ~150-168 us twice). BM=64, BN=256, BK=32,
// 256 thr, 8x8 micro-tile.
// ---------------------------------------------------------------------------
__global__ __launch_bounds__(256)
void xu_gemm(const float* __restrict__ x, const float* __restrict__ U,
             const float* __restrict__ bias, float* __restrict__ P)
{
    __shared__ float As[32][64];   // [k][m] transposed A tile
    __shared__ float Bs[32][256];  // [k][n]
    const int tid = threadIdx.x;
    const int tr = tid >> 5;   // 0..7
    const int tc = tid & 31;   // 0..31
    const long rowBase = (long)blockIdx.x * 64;

    float acc[8][8];
#pragma unroll
    for (int r = 0; r < 8; ++r)
#pragma unroll
        for (int c = 0; c < 8; ++c) acc[r][c] = 0.f;

    for (int k0 = 0; k0 < 256; k0 += 32) {
#pragma unroll
        for (int s = 0; s < 2; ++s) {
            int idx = tid * 2 + s;
            int r   = idx >> 3;          // 0..63
            int kq  = idx & 7;           // k-offset kq*4
            float4 v = *(const float4*)&x[(rowBase + r) * 256 + k0 + kq * 4];
            As[kq*4+0][r] = v.x;
            As[kq*4+1][r] = v.y;
            As[kq*4+2][r] = v.z;
            As[kq*4+3][r] = v.w;
        }
#pragma unroll
        for (int s = 0; s < 8; ++s) {
            int idx = tid + s * 256;
            int kk  = idx >> 6;
            int c4  = idx & 63;
            *(float4*)&Bs[kk][c4*4] = *(const float4*)&U[(k0 + kk) * 256 + c4*4];
        }
        __syncthreads();
#pragma unroll
        for (int kk = 0; kk < 32; ++kk) {
            float4 a0 = *(const float4*)&As[kk][tr*4];
            float4 a1 = *(const float4*)&As[kk][tr*4 + 32];
            float4 b0 = *(const float4*)&Bs[kk][tc*4];
            float4 b1 = *(const float4*)&Bs[kk][tc*4 + 128];
            float av[8] = {a0.x,a0.y,a0.z,a0.w,a1.x,a1.y,a1.z,a1.w};
            float bv[8] = {b0.x,b0.y,b0.z,b0.w,b1.x,b1.y,b1.z,b1.w};
#pragma unroll
            for (int r = 0; r < 8; ++r)
#pragma unroll
                for (int c = 0; c < 8; ++c)
                    acc[r][c] = fmaf(av[r], bv[c], acc[r][c]);
        }
        __syncthreads();
    }
    float4 bb0 = *(const float4*)&bias[tc*4];
    float4 bb1 = *(const float4*)&bias[tc*4 + 128];
#pragma unroll
    for (int r = 0; r < 8; ++r) {
        long row = rowBase + (r < 4 ? (tr*4 + r) : (32 + tr*4 + (r - 4)));
        float4 lo = make_float4(acc[r][0] + bb0.x, acc[r][1] + bb0.y,
                                acc[r][2] + bb0.z, acc[r][3] + bb0.w);
        float4 hi = make_float4(acc[r][4] + bb1.x, acc[r][5] + bb1.y,
                                acc[r][6] + bb1.z, acc[r][7] + bb1.w);
        *(float4*)&P[row * 256 + tc*4]       = lo;
        *(float4*)&P[row * 256 + tc*4 + 128] = hi;
    }
}

// ---------------------------------------------------------------------------
// Kernel B: sequential scan, 1 block/row, 1024 thr = 16 waves.
//   Mechanism under test: LDS-FORCED OCCUPANCY. An 84 KB live LDS pad
//   raises the block's LDS footprint to ~86 KB > 80 KB -> only 1
//   workgroup/CU fits -> achievable occupancy 4 waves/EU -> the backend's
//   default RA budget becomes 128 VGPR (512/4) with no attribute
//   cooperation needed. r4/r5 measured the failure mode this fixes: at the
//   default 64-VGPR target the 64-float W fragment lives in L2-resident
//   scratch and is re-read every step (~475ns/step => ~950us scan).
//   W must be register-resident: any >=20-float/thread LDS share of W is
//   DS-pipe-bound (128KB/CU/step vs ~85-128 B/cy) — no fallback worth it.
//   The pad is kept alive by referencing its address in an empty asm.
//   W held as 64 SCALAR floats, each asm-pinned (remat illegal).
//   Mapping: q = (tid>>3)&7 (k-octant, lane bits 3..5),
//            jp = (tid>>6)*8 + (tid&7) (column pair -> cols 2jp, 2jp+1).
//   shfl_xor 8/16/32 reduces the 8 K-split partials in-wave; a wave reads
//   only 8 distinct float4s/slot from LDS (HW broadcast), rotated chunk
//   order c=(i+q)&7 -> conflict-free (SQ_LDS_BANK_CONFLICT=0 measured).
//   Depth-2 P prefetch; scan_out[t-1] written at top of step t.
// ---------------------------------------------------------------------------
typedef float f32x2 __attribute__((ext_vector_type(2)));

__global__ __launch_bounds__(1024)
void rnn_scan(const float* __restrict__ s0, const float* __restrict__ W,
              float* __restrict__ out)
{
    __shared__ __align__(16) float sb0[256];
    __shared__ __align__(16) float sb1[256];
    __shared__ __align__(16) float ldspad[21504];   // 84 KB occupancy limiter

    const int tid = threadIdx.x;
    // Keep the pad referenced so it is allocated (cannot be DCE'd); costs
    // one address computation, no memory traffic.
    asm volatile("" : : "v"(&ldspad[tid]));

    const int q   = (tid >> 3) & 7;                // k in [q*32, q*32+32)
    const int jp  = ((tid >> 6) << 3) | (tid & 7); // 0..127 -> cols 2jp,2jp+1
    const int row = blockIdx.x;

    // wA[4*i+u] = W[q*32 + c*4 + u][2jp], wB -> col 2jp+1,  c = (i+q)&7
    float wA[32], wB[32];
#pragma unroll
    for (int i = 0; i < 8; ++i) {
        int c = (i + q) & 7;
#pragma unroll
        for (int u = 0; u < 4; ++u) {
            f32x2 wv = *(const f32x2*)&W[(q*32 + c*4 + u) * 256 + 2*jp];
            wA[4*i+u] = wv.x;
            wB[4*i+u] = wv.y;
        }
    }
    // Pin every scalar in a VGPR: asm redefines the value, remat illegal.
#pragma unroll
    for (int i = 0; i < 32; ++i) {
        asm volatile("" : "+v"(wA[i]));
        asm volatile("" : "+v"(wB[i]));
    }

    float* scanP = out + BDIM * DDIM + (long)row * TDIM * DDIM;

    f32x2 pa = *(const f32x2*)&scanP[2*jp];          // P[0]
    f32x2 pb = *(const f32x2*)&scanP[256 + 2*jp];    // P[1]

    if (tid < 64)
        ((float4*)sb0)[tid] = ((const float4*)(s0 + row * 256))[tid];
    __syncthreads();

#define BODY(T, SIN, SOUT, PREG)                                              \
  {                                                                           \
    if ((T) > 0 && (tid & 63) < 4) {         /* scan_out[T-1], 4 lanes/wave */\
        int fi = ((tid >> 6) << 2) + (tid & 63);                              \
        float4 h4 = ((const float4*)(SIN))[fi];                               \
        *(float4*)&scanP[(long)((T) - 1) * 256 + fi * 4] = h4;                \
    }                                                                         \
    const float4* s4p = (const float4*)(SIN);                                 \
    float ax0 = 0.f, ax1 = 0.f, ay0 = 0.f, ay1 = 0.f;                         \
    _Pragma("unroll")                                                         \
    for (int i = 0; i < 8; ++i) {                                             \
        float4 sv = s4p[q * 8 + ((i + q) & 7)];  /* broadcast + no conflict */\
        ax0 = fmaf(sv.x, wA[4*i],   ax0); ay0 = fmaf(sv.x, wB[4*i],   ay0);   \
        ax1 = fmaf(sv.y, wA[4*i+1], ax1); ay1 = fmaf(sv.y, wB[4*i+1], ay1);   \
        ax0 = fmaf(sv.z, wA[4*i+2], ax0); ay0 = fmaf(sv.z, wB[4*i+2], ay0);   \
        ax1 = fmaf(sv.w, wA[4*i+3], ax1); ay1 = fmaf(sv.w, wB[4*i+3], ay1);   \
    }                                                                         \
    float zx = ax0 + ax1, zy = ay0 + ay1;                                     \
    zx += __shfl_xor(zx, 8);  zy += __shfl_xor(zy, 8);                        \
    zx += __shfl_xor(zx, 16); zy += __shfl_xor(zy, 16);                       \
    zx += (PREG).x + __shfl_xor(zx, 32);                                      \
    zy += (PREG).y + __shfl_xor(zy, 32);                                      \
    float hx = tanh_fast(zx), hy = tanh_fast(zy);                             \
    if (q == 0) { f32x2 h2; h2.x = hx; h2.y = hy;                             \
                  *(f32x2*)&(SOUT)[2*jp] = h2; }                              \
    __syncthreads();                                                          \
  }

    for (int t = 0; t < TDIM; t += 2) {
        // depth-2 prefetch: consumed two iterations from now
        f32x2 pnA = *(const f32x2*)&scanP[(long)((t + 2) & 1023) * 256 + 2*jp];
        f32x2 pnB = *(const f32x2*)&scanP[(long)((t + 3) & 1023) * 256 + 2*jp];
        BODY(t,     sb0, sb1, pa);
        BODY(t + 1, sb1, sb0, pb);
        pa = pnA; pb = pnB;
    }

    // scan_out[1023] + final state (state lives in sb0 after 1024 steps)
    if (tid < 64) {
        float4 h4 = ((const float4*)sb0)[tid];
        *(float4*)&scanP[(long)(TDIM - 1) * 256 + tid * 4] = h4;
        *(float4*)&out[row * 256 + tid * 4] = h4;
    }
}

extern "C" void kernel_launch(void* const* d_in, const int* in_sizes, int n_in,
                              void* d_out, int out_size, void* d_ws, size_t ws_size,
                              hipStream_t stream) {
    (void)in_sizes; (void)n_in; (void)out_size; (void)d_ws; (void)ws_size;
    const float* s0 = (const float*)d_in[0];
    const float* x  = (const float*)d_in[1];
    const float* W  = (const float*)d_in[2];
    const float* U  = (const float*)d_in[3];
    const float* b  = (const float*)d_in[4];
    float* out = (float*)d_out;
    float* P   = out + BDIM * DDIM;   // scan_out region doubles as P buffer

    xu_gemm<<<dim3(65536 / 64), dim3(256), 0, stream>>>(x, U, b, P);
    rnn_scan<<<dim3(BDIM), dim3(1024), 0, stream>>>(s0, W, out);
}